// Round 6
// baseline (676.842 us; speedup 1.0000x reference)
//
#include <hip/hip_runtime.h>
#include <hip/hip_fp16.h>

typedef short short8 __attribute__((ext_vector_type(8)));
typedef float f32x16 __attribute__((ext_vector_type(16)));

#define DIMS   256
#define KCODES 8192
#define NTOK   32768
#define BM     128
#define BN     128
#define NTILES 64
#define MARGIN 0.75f
#define CAP    3072

__device__ __forceinline__ unsigned short f2bf(float f) {
    unsigned u = __builtin_bit_cast(unsigned, f);
    return (unsigned short)((u + 0x7FFFu + ((u >> 16) & 1u)) >> 16);   // RNE
}
__device__ __forceinline__ unsigned fenc(float f) {        // order-preserving float->uint
    unsigned u = __builtin_bit_cast(unsigned, f);
    return ((int)u >= 0) ? (u | 0x80000000u) : ~u;
}
__device__ __forceinline__ float fdec(unsigned e) {
    unsigned u = (e & 0x80000000u) ? (e ^ 0x80000000u) : ~e;
    return __builtin_bit_cast(float, u);
}
__device__ __forceinline__ __half2 hmin2(__half2 a, __half2 b) {
    __half2 r;
    r.x = __hmin(a.x, b.x);
    r.y = __hmin(a.y, b.y);
    return r;
}

// fused: c2[k] = ||cb[k]||^2 and optional fp32->bf16 convert. 4 rows/block.
__global__ __launch_bounds__(256) void prep_kernel(const float* __restrict__ cb,
                                                   float* __restrict__ c2,
                                                   unsigned short* __restrict__ cbbf,
                                                   int do_conv) {
    int row  = blockIdx.x * 4 + (threadIdx.x >> 6);
    int lane = threadIdx.x & 63;
    float4 v = *(const float4*)(cb + (size_t)row * DIMS + (size_t)lane * 4);
    if (do_conv) {
        ushort4 s;
        s.x = f2bf(v.x); s.y = f2bf(v.y); s.z = f2bf(v.z); s.w = f2bf(v.w);
        *(ushort4*)(cbbf + (size_t)row * DIMS + (size_t)lane * 4) = s;
    }
    float s = v.x * v.x + v.y * v.y + v.z * v.z + v.w * v.w;
#pragma unroll
    for (int off = 32; off > 0; off >>= 1) s += __shfl_down(s, off);
    if (lane == 0) c2[row] = s;
}

template <bool WSBF>
__global__ __launch_bounds__(512, 2) void vq_main(const float* __restrict__ h,
                                                  const float* __restrict__ cb,
                                                  const unsigned short* __restrict__ cbbf,
                                                  const float* __restrict__ c2g,
                                                  float* __restrict__ out_q,
                                                  float* __restrict__ out_idx) {
    // Bs layout: LDS 16B-chunk slot f = r*32 + j holds global k-chunk (j ^ (r&7)) of
    // tile-local code row r. DMA LDS side is linear (wave-uniform base + lane*16);
    // the swizzle lives on the global gather address. Read of k-chunk ch of row rr:
    // slot rr*32 + (ch ^ (rr&7)) -> 8 lanes per 4-bank group per ds_read_b128 =
    // structural minimum, conflict-free, no padding (DMA-compatible).
    __shared__ short8 Bs[2][4096];               // 2 x 64 KB, double-buffered
    __shared__ unsigned mrunE[BM];               // fenc-encoded per-token running min
    __shared__ unsigned list[CAP];               // 12 KB candidate list
    __shared__ unsigned long long best64[BM];
    __shared__ int fin[BM];
    __shared__ int cnt;

    const int tid   = threadIdx.x;
    const int lane  = tid & 63;
    const int wave  = tid >> 6;
    const int l31   = lane & 31;
    const int khalf = lane >> 5;
    const int wm    = wave >> 2;     // 0..1 : 64-token half
    const int wn    = wave & 3;      // 0..3 : 32-code stripe
    const int tokBase = blockIdx.x * BM;

    if (tid < BM) { mrunE[tid] = 0xFFFFFFFFu; best64[tid] = ~0ULL; }
    if (tid == 0) cnt = 0;

    // ---- A fragments in registers: 64 tokens x 256 dims (128 VGPR) ----
    // 32x32x16 A-layout: row = lane&31, k = khalf*8 + j (same k-decomp as B: safe)
    short8 afr[2][16];
#pragma unroll
    for (int i = 0; i < 2; i++) {
        const float* base = h + (size_t)(tokBase + wm * 64 + i * 32 + l31) * DIMS + khalf * 8;
#pragma unroll
        for (int s = 0; s < 16; s++) {
            float4 v0 = *(const float4*)(base + s * 16);
            float4 v1 = *(const float4*)(base + s * 16 + 4);
            short8 v;
            v[0] = f2bf(v0.x); v[1] = f2bf(v0.y); v[2] = f2bf(v0.z); v[3] = f2bf(v0.w);
            v[4] = f2bf(v1.x); v[5] = f2bf(v1.y); v[6] = f2bf(v1.z); v[7] = f2bf(v1.w);
            afr[i][s] = v;
        }
    }

    // ---- staging: tile t (64 KB = 4096 chunks) -> buffer buf ----
    auto stage = [&](int t, int buf) {
#pragma unroll
        for (int q = 0; q < 8; q++) {
            int n = wave * 8 + q;          // staging instr index 0..63 (wave-uniform)
            int c = n * 64 + lane;         // chunk 0..4095
            int r = c >> 5;                // tile-local code row (32 chunks/row)
            int j = c & 31;
            int kc = j ^ (r & 7);          // swizzled k-chunk
            if constexpr (WSBF) {
                const unsigned short* g = cbbf + (size_t)(t * BN + r) * DIMS + kc * 8;
                __builtin_amdgcn_global_load_lds(
                    (const __attribute__((address_space(1))) unsigned int*)g,
                    (__attribute__((address_space(3))) unsigned int*)&Bs[buf][n * 64],
                    16, 0, 0);
            } else {
                const float4* gp = (const float4*)(cb + (size_t)(t * BN + r) * DIMS + kc * 8);
                float4 v0 = gp[0], v1 = gp[1];
                short8 v;
                v[0] = f2bf(v0.x); v[1] = f2bf(v0.y); v[2] = f2bf(v0.z); v[3] = f2bf(v0.w);
                v[4] = f2bf(v1.x); v[5] = f2bf(v1.y); v[6] = f2bf(v1.z); v[7] = f2bf(v1.w);
                Bs[buf][c] = v;
            }
        }
    };
    stage(0, 0);

    __half2 vmin2[2][8], thr2[2][8];
#pragma unroll
    for (int i = 0; i < 2; i++)
#pragma unroll
        for (int p = 0; p < 8; p++) {
            vmin2[i][p] = __floats2half2_rn(65504.f, 65504.f);
            thr2[i][p]  = __floats2half2_rn(-65504.f, -65504.f);
        }

    // ---- main loop: 64 tiles + redo of tile 0 (emission vs final thresholds) ----
#pragma unroll 1
    for (int it = 0; it <= NTILES; ++it) {
        const int t   = (it == NTILES) ? 0 : it;
        const int cur = it & 1;
        __syncthreads();   // readers of buf[cur^1] done; DMA for buf[cur] (issued it-1) drained
        if (it < NTILES) stage((it + 1 == NTILES) ? 0 : it + 1, cur ^ 1);  // in flight this tile

        int code  = t * BN + wn * 32 + l31;
        float c2v = c2g[code];

        f32x16 acc0 = {0,0,0,0,0,0,0,0,0,0,0,0,0,0,0,0};
        f32x16 acc1 = {0,0,0,0,0,0,0,0,0,0,0,0,0,0,0,0};
        const int rr = wn * 32 + l31;
        const int rbase = rr * 32, rx = rr & 7;
#pragma unroll
        for (int s = 0; s < 16; s++) {
            short8 b = Bs[cur][rbase + ((2 * s + khalf) ^ rx)];
            acc0 = __builtin_amdgcn_mfma_f32_32x32x16_bf16(afr[0][s], b, acc0, 0, 0, 0);
            acc1 = __builtin_amdgcn_mfma_f32_32x32x16_bf16(afr[1][s], b, acc1, 0, 0, 0);
        }

        // scores: s = c2[code] - 2*xc ; C/D: col=lane&31, row=(reg&3)+8*(reg>>2)+4*khalf
        const bool emit = (it > 0);
#pragma unroll
        for (int i = 0; i < 2; i++) {
            const f32x16 A = i ? acc1 : acc0;
            const int tb = wm * 64 + i * 32 + 4 * khalf;
#pragma unroll
            for (int p = 0; p < 8; p++) {
                float s0 = fmaf(-2.f, A[2 * p],     c2v);
                float s1 = fmaf(-2.f, A[2 * p + 1], c2v);
                if (it < NTILES)
                    vmin2[i][p] = hmin2(vmin2[i][p], __floats2half2_rn(s0, s1));
                if (emit) {
                    float2 th = __half22float2(thr2[i][p]);
                    if (s0 <= th.x) {
                        int tok = tb + ((2 * p) & 3) + 8 * (p >> 1);
                        int pos = atomicAdd(&cnt, 1);
                        if (pos < CAP) list[pos] = (unsigned)((tok << 13) | code);
                    }
                    if (s1 <= th.y) {
                        int tok = tb + ((2 * p + 1) & 3) + 8 * (p >> 1);
                        int pos = atomicAdd(&cnt, 1);
                        if (pos < CAP) list[pos] = (unsigned)((tok << 13) | code);
                    }
                }
            }
        }

        // every-8-tiles: cross-lane reduce vmin -> mrunE, refresh thresholds
        if (it < NTILES && (it & 7) == 0) {
#pragma unroll
            for (int i = 0; i < 2; i++) {
                const int tb = wm * 64 + i * 32 + 4 * khalf;
#pragma unroll
                for (int p = 0; p < 8; p++) {
                    __half2 v = vmin2[i][p];
#pragma unroll
                    for (int m = 1; m < 32; m <<= 1) {
                        int o = __shfl_xor(__builtin_bit_cast(int, v), m);
                        v = hmin2(v, __builtin_bit_cast(__half2, o));
                    }
                    if (l31 == 0) {
                        float2 f = __half22float2(v);
                        int tok0 = tb + ((2 * p) & 3) + 8 * (p >> 1);
                        int tok1 = tb + ((2 * p + 1) & 3) + 8 * (p >> 1);
                        atomicMin(&mrunE[tok0], fenc(f.x));
                        atomicMin(&mrunE[tok1], fenc(f.y));
                    }
                }
            }
            __syncthreads();   // atomics visible
#pragma unroll
            for (int i = 0; i < 2; i++) {
                const int tb = wm * 64 + i * 32 + 4 * khalf;
#pragma unroll
                for (int p = 0; p < 8; p++) {
                    int tok0 = tb + ((2 * p) & 3) + 8 * (p >> 1);
                    int tok1 = tb + ((2 * p + 1) & 3) + 8 * (p >> 1);
                    thr2[i][p] = __floats2half2_rn(fdec(mrunE[tok0]) + MARGIN,
                                                   fdec(mrunE[tok1]) + MARGIN);
                }
            }
        }
    }
    __syncthreads();   // list/cnt final

    // ---- exact fp32 rescore: one wave-dot per candidate (coalesced) ----
    int n = cnt; if (n > CAP) n = CAP;
    for (int p = wave; p < n; p += 8) {
        unsigned e = list[p];
        int tok = (int)(e >> 13), code = (int)(e & 8191);
        float4 hv = *(const float4*)(h + (size_t)(tokBase + tok) * DIMS + lane * 4);
        float4 cv = *(const float4*)(cb + (size_t)code * DIMS + lane * 4);
        float d = hv.x * cv.x + hv.y * cv.y + hv.z * cv.z + hv.w * cv.w;
#pragma unroll
        for (int m = 1; m < 64; m <<= 1) d += __shfl_xor(d, m);
        float s = c2g[code] - 2.f * d;
        if (lane == 0)
            atomicMin(&best64[tok], ((unsigned long long)fenc(s) << 32) | (unsigned)code);
    }
    __syncthreads();

    if (tid < BM) {
        int idx = (int)(best64[tid] & 0xFFFFFFFFULL);
        if ((unsigned)idx >= (unsigned)KCODES) idx = 0;   // never fault on a dropped token
        fin[tid] = idx;
        out_idx[tokBase + tid] = (float)idx;
    }
    __syncthreads();
    for (int e2 = tid; e2 < BM * (DIMS / 4); e2 += 512) {
        int r = e2 >> 6, c4 = e2 & 63;
        float4 v = *(const float4*)(cb + (size_t)fin[r] * DIMS + c4 * 4);
        *(float4*)(out_q + (size_t)(tokBase + r) * DIMS + c4 * 4) = v;
    }
}

extern "C" void kernel_launch(void* const* d_in, const int* in_sizes, int n_in,
                              void* d_out, int out_size, void* d_ws, size_t ws_size,
                              hipStream_t stream) {
    const float* h  = (const float*)d_in[0];   // [32768, 256]
    const float* cb = (const float*)d_in[1];   // [8192, 256]
    float* out_q   = (float*)d_out;
    float* out_idx = (float*)d_out + (size_t)NTOK * DIMS;

    float* c2 = (float*)d_ws;                                       // 32 KB
    unsigned short* cbbf = (unsigned short*)((char*)d_ws + 32768);  // 4 MB
    const size_t needed = 32768 + (size_t)KCODES * DIMS * 2;
    const int wsbf = (ws_size >= needed) ? 1 : 0;

    prep_kernel<<<KCODES / 4, 256, 0, stream>>>(cb, c2, cbbf, wsbf);
    if (wsbf)
        vq_main<true><<<NTOK / BM, 512, 0, stream>>>(h, cb, cbbf, c2, out_q, out_idx);
    else
        vq_main<false><<<NTOK / BM, 512, 0, stream>>>(h, cb, (const unsigned short*)nullptr, c2, out_q, out_idx);
}

// Round 7
// 561.924 us; speedup vs baseline: 1.2045x; 1.2045x over previous
//
#include <hip/hip_runtime.h>
#include <hip/hip_fp16.h>

typedef short short8 __attribute__((ext_vector_type(8)));
typedef float f32x4 __attribute__((ext_vector_type(4)));

#define DIMS   256
#define KCODES 8192
#define NTOK   32768
#define BM     64      // tokens per block
#define BN     128     // codes per tile
#define NTILES 64
#define MARGIN 0.75f
#define CAP    2048

__device__ __forceinline__ unsigned short f2bf(float f) {
    unsigned u = __builtin_bit_cast(unsigned, f);
    return (unsigned short)((u + 0x7FFFu + ((u >> 16) & 1u)) >> 16);   // RNE
}
__device__ __forceinline__ unsigned fenc(float f) {        // order-preserving float->uint
    unsigned u = __builtin_bit_cast(unsigned, f);
    return ((int)u >= 0) ? (u | 0x80000000u) : ~u;
}
__device__ __forceinline__ float fdec(unsigned e) {
    unsigned u = (e & 0x80000000u) ? (e ^ 0x80000000u) : ~e;
    return __builtin_bit_cast(float, u);
}
__device__ __forceinline__ __half2 hmin2(__half2 a, __half2 b) {
    __half2 r;
    r.x = __hmin(a.x, b.x);
    r.y = __hmin(a.y, b.y);
    return r;
}

// fused: c2[k] = ||cb[k]||^2 and optional fp32->bf16 convert. 4 rows/block.
__global__ __launch_bounds__(256) void prep_kernel(const float* __restrict__ cb,
                                                   float* __restrict__ c2,
                                                   unsigned short* __restrict__ cbbf,
                                                   int do_conv) {
    int row  = blockIdx.x * 4 + (threadIdx.x >> 6);
    int lane = threadIdx.x & 63;
    float4 v = *(const float4*)(cb + (size_t)row * DIMS + (size_t)lane * 4);
    if (do_conv) {
        ushort4 s;
        s.x = f2bf(v.x); s.y = f2bf(v.y); s.z = f2bf(v.z); s.w = f2bf(v.w);
        *(ushort4*)(cbbf + (size_t)row * DIMS + (size_t)lane * 4) = s;
    }
    float s = v.x * v.x + v.y * v.y + v.z * v.z + v.w * v.w;
#pragma unroll
    for (int off = 32; off > 0; off >>= 1) s += __shfl_down(s, off);
    if (lane == 0) c2[row] = s;
}

template <bool WSBF>
__global__ __launch_bounds__(256, 2) void vq_main(const float* __restrict__ h,
                                                  const float* __restrict__ cb,
                                                  const unsigned short* __restrict__ cbbf,
                                                  const float* __restrict__ c2g,
                                                  float* __restrict__ out_q,
                                                  float* __restrict__ out_idx) {
    // Bs: 16B-chunk slot r*32+x holds global k-chunk (x ^ (r&7)) of tile row r.
    // DMA LDS side linear (wave-uniform base + lane*16); swizzle on global addr.
    // Read of k-chunk ch of row rr: slot rr*32 + (ch ^ (rr&7)) -> 8 lanes per
    // 4-bank group per ds_read_b128 = structural minimum, conflict-free.
    __shared__ short8 Bs[4096];                  // 64 KB, single-buffered
    __shared__ unsigned mrunE[BM];               // fenc-encoded running min per token
    __shared__ unsigned list[CAP];               // 8 KB candidate list
    __shared__ unsigned long long best64[BM];
    __shared__ int fin[BM];
    __shared__ int cnt;

    const int tid  = threadIdx.x;
    const int lane = tid & 63;
    const int wave = tid >> 6;       // 0..3
    const int l15  = lane & 15;
    const int quad = lane >> 4;
    const int wm   = wave >> 1;      // 0..1 : 32-token half
    const int wn   = wave & 1;       // 0..1 : 64-code stripe
    const int tokBase = blockIdx.x * BM;

    if (tid < BM) { mrunE[tid] = 0xFFFFFFFFu; best64[tid] = ~0ULL; }
    if (tid == 0) cnt = 0;

    // ---- A fragments in registers: 32 tokens x 256 dims per wave (64 VGPR) ----
    // 16x16x32 layout (R3-verified): row=l15, k = kk*32 + quad*8 + e
    short8 afr[2][8];
#pragma unroll
    for (int i = 0; i < 2; i++) {
        const float* base = h + (size_t)(tokBase + wm * 32 + i * 16 + l15) * DIMS + quad * 8;
#pragma unroll
        for (int kk = 0; kk < 8; kk++) {
            float4 v0 = *(const float4*)(base + kk * 32);
            float4 v1 = *(const float4*)(base + kk * 32 + 4);
            short8 v;
            v[0] = f2bf(v0.x); v[1] = f2bf(v0.y); v[2] = f2bf(v0.z); v[3] = f2bf(v0.w);
            v[4] = f2bf(v1.x); v[5] = f2bf(v1.y); v[6] = f2bf(v1.z); v[7] = f2bf(v1.w);
            afr[i][kk] = v;
        }
    }

    // ---- staging: tile t (64 KB = 4096 chunks) ----
    auto stage = [&](int t) {
        if constexpr (WSBF) {
#pragma unroll
            for (int q = 0; q < 16; q++) {
                int n = wave * 16 + q;         // wave-uniform instr index 0..63
                int c = n * 64 + lane;         // chunk 0..4095
                int r = c >> 5;
                int kc = (c & 31) ^ (r & 7);   // swizzled global k-chunk
                const unsigned short* g = cbbf + (size_t)(t * BN + r) * DIMS + kc * 8;
                __builtin_amdgcn_global_load_lds(
                    (const __attribute__((address_space(1))) unsigned int*)g,
                    (__attribute__((address_space(3))) unsigned int*)&Bs[n * 64],
                    16, 0, 0);
            }
        } else {
#pragma unroll
            for (int q = 0; q < 16; q++) {
                int c = tid + q * 256;
                int r = c >> 5;
                int kc = (c & 31) ^ (r & 7);
                const float4* gp = (const float4*)(cb + (size_t)(t * BN + r) * DIMS + kc * 8);
                float4 v0 = gp[0], v1 = gp[1];
                short8 v;
                v[0] = f2bf(v0.x); v[1] = f2bf(v0.y); v[2] = f2bf(v0.z); v[3] = f2bf(v0.w);
                v[4] = f2bf(v1.x); v[5] = f2bf(v1.y); v[6] = f2bf(v1.z); v[7] = f2bf(v1.w);
                Bs[c] = v;
            }
        }
    };

    f32x4 acc[2][4];
    __half2 vmin2[2][2], thr2[2][2];
#pragma unroll
    for (int i = 0; i < 2; i++)
#pragma unroll
        for (int r2 = 0; r2 < 2; r2++) {
            vmin2[i][r2] = __floats2half2_rn(65504.f, 65504.f);
            thr2[i][r2]  = __floats2half2_rn(-65504.f, -65504.f);
        }

    // score tile st from acc; emit candidates; fold refresh atomics when asked
    auto score = [&](int st, bool emit, bool refresh) {
#pragma unroll
        for (int i = 0; i < 2; i++) {
#pragma unroll
            for (int j = 0; j < 4; j++) {
                int code = st * BN + wn * 64 + j * 16 + l15;
                float cc = c2g[code];
                float s0 = fmaf(-2.f, acc[i][j][0], cc);
                float s1 = fmaf(-2.f, acc[i][j][1], cc);
                float s2 = fmaf(-2.f, acc[i][j][2], cc);
                float s3 = fmaf(-2.f, acc[i][j][3], cc);
                vmin2[i][0] = hmin2(vmin2[i][0], __floats2half2_rn(s0, s1));
                vmin2[i][1] = hmin2(vmin2[i][1], __floats2half2_rn(s2, s3));
                if (emit) {
                    int tb = wm * 32 + i * 16 + quad * 4;
                    float2 ta = __half22float2(thr2[i][0]);
                    float2 tbv = __half22float2(thr2[i][1]);
                    if (s0 <= ta.x) { int p = atomicAdd(&cnt, 1); if (p < CAP) list[p] = (unsigned)(((tb + 0) << 13) | code); }
                    if (s1 <= ta.y) { int p = atomicAdd(&cnt, 1); if (p < CAP) list[p] = (unsigned)(((tb + 1) << 13) | code); }
                    if (s2 <= tbv.x) { int p = atomicAdd(&cnt, 1); if (p < CAP) list[p] = (unsigned)(((tb + 2) << 13) | code); }
                    if (s3 <= tbv.y) { int p = atomicAdd(&cnt, 1); if (p < CAP) list[p] = (unsigned)(((tb + 3) << 13) | code); }
                }
            }
        }
        if (refresh) {
#pragma unroll
            for (int i = 0; i < 2; i++)
#pragma unroll
                for (int r2 = 0; r2 < 2; r2++) {
                    __half2 v = vmin2[i][r2];
#pragma unroll
                    for (int m = 1; m < 16; m <<= 1) {
                        int o = __shfl_xor(__builtin_bit_cast(int, v), m);
                        v = hmin2(v, __builtin_bit_cast(__half2, o));
                    }
                    if (l15 == 0) {
                        float2 f = __half22float2(v);
                        int tok = wm * 32 + i * 16 + quad * 4 + 2 * r2;
                        atomicMin(&mrunE[tok],     fenc(f.x));
                        atomicMin(&mrunE[tok + 1], fenc(f.y));
                    }
                }
        }
    };

    // ---- main loop: stage t -> score t-1 (hides DMA) -> barrier -> MFMA t ----
#pragma unroll 1
    for (int it = 0; it <= NTILES; ++it) {
        const int st = it - 1;
        const bool refresh = (st >= 0) && ((st & 7) == 0);
        __syncthreads();   // (a) prev MFMA's LDS reads done before DMA overwrites Bs
        stage((it < NTILES) ? it : 0);          // it==NTILES restages tile 0 for epilogue
        if (st >= 0) score(st, st > 0, refresh);
        __syncthreads();   // (b) per-wave vmcnt(0) before barrier -> all DMA landed; atomics visible
        if (refresh) {
#pragma unroll
            for (int i = 0; i < 2; i++)
#pragma unroll
                for (int r2 = 0; r2 < 2; r2++) {
                    int tok = wm * 32 + i * 16 + quad * 4 + 2 * r2;
                    thr2[i][r2] = __floats2half2_rn(fdec(mrunE[tok]) + MARGIN,
                                                    fdec(mrunE[tok + 1]) + MARGIN);
                }
        }
        // MFMA: 8 independent chains (2 row-blocks x 4 col-blocks), K=256
#pragma unroll
        for (int i = 0; i < 2; i++)
#pragma unroll
            for (int j = 0; j < 4; j++) acc[i][j] = (f32x4){0.f, 0.f, 0.f, 0.f};
#pragma unroll
        for (int s = 0; s < 8; s++) {
            short8 b[4];
#pragma unroll
            for (int j = 0; j < 4; j++) {
                int rr = wn * 64 + j * 16 + l15;
                b[j] = Bs[rr * 32 + ((s * 4 + quad) ^ (rr & 7))];
            }
#pragma unroll
            for (int i = 0; i < 2; i++)
#pragma unroll
                for (int j = 0; j < 4; j++)
                    acc[i][j] = __builtin_amdgcn_mfma_f32_16x16x32_bf16(afr[i][s], b[j], acc[i][j], 0, 0, 0);
        }
    }
    // epilogue: score tile 0 (fresh acc) against final thresholds, with emission
    score(0, true, false);
    __syncthreads();   // list/cnt final

    // ---- exact fp32 rescore: one wave-dot per candidate (coalesced) ----
    int n = cnt; if (n > CAP) n = CAP;
    for (int p = wave; p < n; p += 4) {
        unsigned e = list[p];
        int tok = (int)(e >> 13), code = (int)(e & 8191);
        float4 hv = *(const float4*)(h + (size_t)(tokBase + tok) * DIMS + lane * 4);
        float4 cv = *(const float4*)(cb + (size_t)code * DIMS + lane * 4);
        float d = hv.x * cv.x + hv.y * cv.y + hv.z * cv.z + hv.w * cv.w;
#pragma unroll
        for (int m = 1; m < 64; m <<= 1) d += __shfl_xor(d, m);
        float s = c2g[code] - 2.f * d;
        if (lane == 0)
            atomicMin(&best64[tok], ((unsigned long long)fenc(s) << 32) | (unsigned)code);
    }
    __syncthreads();

    if (tid < BM) {
        int idx = (int)(best64[tid] & 0xFFFFFFFFULL);
        if ((unsigned)idx >= (unsigned)KCODES) idx = 0;   // never fault on a dropped token
        fin[tid] = idx;
        out_idx[tokBase + tid] = (float)idx;
    }
    __syncthreads();
    for (int e2 = tid; e2 < BM * (DIMS / 4); e2 += 256) {
        int r = e2 >> 6, c4 = e2 & 63;
        float4 v = *(const float4*)(cb + (size_t)fin[r] * DIMS + c4 * 4);
        *(float4*)(out_q + (size_t)(tokBase + r) * DIMS + c4 * 4) = v;
    }
}

extern "C" void kernel_launch(void* const* d_in, const int* in_sizes, int n_in,
                              void* d_out, int out_size, void* d_ws, size_t ws_size,
                              hipStream_t stream) {
    const float* h  = (const float*)d_in[0];   // [32768, 256]
    const float* cb = (const float*)d_in[1];   // [8192, 256]
    float* out_q   = (float*)d_out;
    float* out_idx = (float*)d_out + (size_t)NTOK * DIMS;

    float* c2 = (float*)d_ws;                                       // 32 KB
    unsigned short* cbbf = (unsigned short*)((char*)d_ws + 32768);  // 4 MB
    const size_t needed = 32768 + (size_t)KCODES * DIMS * 2;
    const int wsbf = (ws_size >= needed) ? 1 : 0;

    prep_kernel<<<KCODES / 4, 256, 0, stream>>>(cb, c2, cbbf, wsbf);
    if (wsbf)
        vq_main<true><<<NTOK / BM, 256, 0, stream>>>(h, cb, cbbf, c2, out_q, out_idx);
    else
        vq_main<false><<<NTOK / BM, 256, 0, stream>>>(h, cb, (const unsigned short*)nullptr, c2, out_q, out_idx);
}

// Round 8
// 560.425 us; speedup vs baseline: 1.2077x; 1.0027x over previous
//
#include <hip/hip_runtime.h>
#include <hip/hip_fp16.h>

typedef short short8 __attribute__((ext_vector_type(8)));
typedef float f32x4 __attribute__((ext_vector_type(4)));

#define DIMS   256
#define KCODES 8192
#define NTOK   32768
#define BM     64      // tokens per block
#define BN     128     // codes per tile
#define NTILES 64
#define MARGIN 0.75f
#define CAP    2048

__device__ __forceinline__ unsigned short f2bf(float f) {
    unsigned u = __builtin_bit_cast(unsigned, f);
    return (unsigned short)((u + 0x7FFFu + ((u >> 16) & 1u)) >> 16);   // RNE
}
__device__ __forceinline__ unsigned fenc(float f) {        // order-preserving float->uint
    unsigned u = __builtin_bit_cast(unsigned, f);
    return ((int)u >= 0) ? (u | 0x80000000u) : ~u;
}
__device__ __forceinline__ float fdec(unsigned e) {
    unsigned u = (e & 0x80000000u) ? (e ^ 0x80000000u) : ~e;
    return __builtin_bit_cast(float, u);
}
__device__ __forceinline__ __half2 hmin2(__half2 a, __half2 b) {
    __half2 r;
    r.x = __hmin(a.x, b.x);
    r.y = __hmin(a.y, b.y);
    return r;
}

// fused: c2[k] = ||cb[k]||^2 and optional fp32->bf16 convert. 4 rows/block.
__global__ __launch_bounds__(256) void prep_kernel(const float* __restrict__ cb,
                                                   float* __restrict__ c2,
                                                   unsigned short* __restrict__ cbbf,
                                                   int do_conv) {
    int row  = blockIdx.x * 4 + (threadIdx.x >> 6);
    int lane = threadIdx.x & 63;
    float4 v = *(const float4*)(cb + (size_t)row * DIMS + (size_t)lane * 4);
    if (do_conv) {
        ushort4 s;
        s.x = f2bf(v.x); s.y = f2bf(v.y); s.z = f2bf(v.z); s.w = f2bf(v.w);
        *(ushort4*)(cbbf + (size_t)row * DIMS + (size_t)lane * 4) = s;
    }
    float s = v.x * v.x + v.y * v.y + v.z * v.z + v.w * v.w;
#pragma unroll
    for (int off = 32; off > 0; off >>= 1) s += __shfl_down(s, off);
    if (lane == 0) c2[row] = s;
}

template <bool WSBF>
__global__ __launch_bounds__(256, 2) void vq_main(const float* __restrict__ h,
                                                  const float* __restrict__ cb,
                                                  const unsigned short* __restrict__ cbbf,
                                                  const float* __restrict__ c2g,
                                                  float* __restrict__ out_q,
                                                  float* __restrict__ out_idx) {
    // Bs: 16B-chunk slot r*32+x holds global k-chunk (x ^ (r&7)) of tile row r.
    // DMA LDS side linear; swizzle on global addr. Conflict-free ds_read_b128.
    __shared__ short8 Bs[4096];                  // 64 KB, single-buffered
    __shared__ unsigned mrunE[BM];               // fenc-encoded running min per token
    __shared__ unsigned list[CAP];               // 8 KB candidate list
    __shared__ unsigned long long best64[BM];
    __shared__ int fin[BM];
    __shared__ int cnt;

    const int tid  = threadIdx.x;
    const int lane = tid & 63;
    const int wave = tid >> 6;       // 0..3
    const int l15  = lane & 15;
    const int quad = lane >> 4;
    const int wm   = wave >> 1;      // 0..1 : 32-token half
    const int wn   = wave & 1;       // 0..1 : 64-code stripe
    const int tokBase = blockIdx.x * BM;
    // XCD-phase-aligned tile order: all blocks on one XCD (empirical bid%8 map)
    // sweep the same tile at the same time -> staging hits that XCD's L2
    // instead of streaming the whole 4MB codebook from L3 per block.
    const int tstart = (blockIdx.x & 7) * (NTILES / 8);

    if (tid < BM) { mrunE[tid] = 0xFFFFFFFFu; best64[tid] = ~0ULL; }
    if (tid == 0) cnt = 0;

    // ---- A fragments in registers: 32 tokens x 256 dims per wave (64 VGPR) ----
    short8 afr[2][8];
#pragma unroll
    for (int i = 0; i < 2; i++) {
        const float* base = h + (size_t)(tokBase + wm * 32 + i * 16 + l15) * DIMS + quad * 8;
#pragma unroll
        for (int kk = 0; kk < 8; kk++) {
            float4 v0 = *(const float4*)(base + kk * 32);
            float4 v1 = *(const float4*)(base + kk * 32 + 4);
            short8 v;
            v[0] = f2bf(v0.x); v[1] = f2bf(v0.y); v[2] = f2bf(v0.z); v[3] = f2bf(v0.w);
            v[4] = f2bf(v1.x); v[5] = f2bf(v1.y); v[6] = f2bf(v1.z); v[7] = f2bf(v1.w);
            afr[i][kk] = v;
        }
    }

    // ---- staging: tile tl (64 KB = 4096 chunks) ----
    auto stage = [&](int tl) {
        if constexpr (WSBF) {
#pragma unroll
            for (int q = 0; q < 16; q++) {
                int n = wave * 16 + q;         // wave-uniform instr index 0..63
                int c = n * 64 + lane;         // chunk 0..4095
                int r = c >> 5;
                int kc = (c & 31) ^ (r & 7);   // swizzled global k-chunk
                const unsigned short* g = cbbf + (size_t)(tl * BN + r) * DIMS + kc * 8;
                __builtin_amdgcn_global_load_lds(
                    (const __attribute__((address_space(1))) unsigned int*)g,
                    (__attribute__((address_space(3))) unsigned int*)&Bs[n * 64],
                    16, 0, 0);
            }
        } else {
#pragma unroll
            for (int q = 0; q < 16; q++) {
                int c = tid + q * 256;
                int r = c >> 5;
                int kc = (c & 31) ^ (r & 7);
                const float4* gp = (const float4*)(cb + (size_t)(tl * BN + r) * DIMS + kc * 8);
                float4 v0 = gp[0], v1 = gp[1];
                short8 v;
                v[0] = f2bf(v0.x); v[1] = f2bf(v0.y); v[2] = f2bf(v0.z); v[3] = f2bf(v0.w);
                v[4] = f2bf(v1.x); v[5] = f2bf(v1.y); v[6] = f2bf(v1.z); v[7] = f2bf(v1.w);
                Bs[c] = v;
            }
        }
    };

    f32x4 acc[2][4];
    __half2 vmin2[2][2], thr2[2][2];
#pragma unroll
    for (int i = 0; i < 2; i++)
#pragma unroll
        for (int r2 = 0; r2 < 2; r2++) {
            vmin2[i][r2] = __floats2half2_rn(65504.f, 65504.f);
            thr2[i][r2]  = __floats2half2_rn(-65504.f, -65504.f);
        }

    // score staged tile tl from acc; emit candidates; fold refresh atomics
    auto score = [&](int tl, bool emit, bool refresh) {
#pragma unroll
        for (int i = 0; i < 2; i++) {
#pragma unroll
            for (int j = 0; j < 4; j++) {
                int code = tl * BN + wn * 64 + j * 16 + l15;
                float cc = c2g[code];
                float s0 = fmaf(-2.f, acc[i][j][0], cc);
                float s1 = fmaf(-2.f, acc[i][j][1], cc);
                float s2 = fmaf(-2.f, acc[i][j][2], cc);
                float s3 = fmaf(-2.f, acc[i][j][3], cc);
                vmin2[i][0] = hmin2(vmin2[i][0], __floats2half2_rn(s0, s1));
                vmin2[i][1] = hmin2(vmin2[i][1], __floats2half2_rn(s2, s3));
                if (emit) {
                    int tb = wm * 32 + i * 16 + quad * 4;
                    float2 ta = __half22float2(thr2[i][0]);
                    float2 tbv = __half22float2(thr2[i][1]);
                    if (s0 <= ta.x) { int p = atomicAdd(&cnt, 1); if (p < CAP) list[p] = (unsigned)(((tb + 0) << 13) | code); }
                    if (s1 <= ta.y) { int p = atomicAdd(&cnt, 1); if (p < CAP) list[p] = (unsigned)(((tb + 1) << 13) | code); }
                    if (s2 <= tbv.x) { int p = atomicAdd(&cnt, 1); if (p < CAP) list[p] = (unsigned)(((tb + 2) << 13) | code); }
                    if (s3 <= tbv.y) { int p = atomicAdd(&cnt, 1); if (p < CAP) list[p] = (unsigned)(((tb + 3) << 13) | code); }
                }
            }
        }
        if (refresh) {
#pragma unroll
            for (int i = 0; i < 2; i++)
#pragma unroll
                for (int r2 = 0; r2 < 2; r2++) {
                    __half2 v = vmin2[i][r2];
#pragma unroll
                    for (int m = 1; m < 16; m <<= 1) {
                        int o = __shfl_xor(__builtin_bit_cast(int, v), m);
                        v = hmin2(v, __builtin_bit_cast(__half2, o));
                    }
                    if (l15 == 0) {
                        float2 f = __half22float2(v);
                        int tok = wm * 32 + i * 16 + quad * 4 + 2 * r2;
                        atomicMin(&mrunE[tok],     fenc(f.x));
                        atomicMin(&mrunE[tok + 1], fenc(f.y));
                    }
                }
        }
    };

    // tile id for iteration index (rotated sweep)
    auto tile_of = [&](int i2) { return (tstart + i2) & (NTILES - 1); };

    // ---- main loop: stage t -> score t-1 (hides DMA) -> barrier -> MFMA t ----
#pragma unroll 1
    for (int it = 0; it <= NTILES; ++it) {
        const int st = it - 1;
        const bool refresh = (st >= 0) && ((st & 7) == 0);
        __syncthreads();   // (a) prev MFMA's LDS reads done before DMA overwrites Bs
        stage(tile_of((it < NTILES) ? it : 0));   // it==NTILES restages first tile
        if (st >= 0) score(tile_of(st), st > 0, refresh);
        __syncthreads();   // (b) vmcnt(0) before barrier -> DMA landed; atomics visible
        if (refresh) {
#pragma unroll
            for (int i = 0; i < 2; i++)
#pragma unroll
                for (int r2 = 0; r2 < 2; r2++) {
                    int tok = wm * 32 + i * 16 + quad * 4 + 2 * r2;
                    thr2[i][r2] = __floats2half2_rn(fdec(mrunE[tok]) + MARGIN,
                                                    fdec(mrunE[tok + 1]) + MARGIN);
                }
        }
        // MFMA: 8 independent chains (2 row-blocks x 4 col-blocks), K=256
#pragma unroll
        for (int i = 0; i < 2; i++)
#pragma unroll
            for (int j = 0; j < 4; j++) acc[i][j] = (f32x4){0.f, 0.f, 0.f, 0.f};
#pragma unroll
        for (int s = 0; s < 8; s++) {
            short8 b[4];
#pragma unroll
            for (int j = 0; j < 4; j++) {
                int rr = wn * 64 + j * 16 + l15;
                b[j] = Bs[rr * 32 + ((s * 4 + quad) ^ (rr & 7))];
            }
#pragma unroll
            for (int i = 0; i < 2; i++)
#pragma unroll
                for (int j = 0; j < 4; j++)
                    acc[i][j] = __builtin_amdgcn_mfma_f32_16x16x32_bf16(afr[i][s], b[j], acc[i][j], 0, 0, 0);
        }
    }
    // epilogue: score first-swept tile (fresh acc) against final thresholds
    score(tile_of(0), true, false);
    __syncthreads();   // list/cnt final

    // ---- exact fp32 rescore: one wave-dot per candidate (coalesced) ----
    int n = cnt; if (n > CAP) n = CAP;
    for (int p = wave; p < n; p += 4) {
        unsigned e = list[p];
        int tok = (int)(e >> 13), code = (int)(e & 8191);
        float4 hv = *(const float4*)(h + (size_t)(tokBase + tok) * DIMS + lane * 4);
        float4 cv = *(const float4*)(cb + (size_t)code * DIMS + lane * 4);
        float d = hv.x * cv.x + hv.y * cv.y + hv.z * cv.z + hv.w * cv.w;
#pragma unroll
        for (int m = 1; m < 64; m <<= 1) d += __shfl_xor(d, m);
        float s = c2g[code] - 2.f * d;
        if (lane == 0)
            atomicMin(&best64[tok], ((unsigned long long)fenc(s) << 32) | (unsigned)code);
    }
    __syncthreads();

    if (tid < BM) {
        int idx = (int)(best64[tid] & 0xFFFFFFFFULL);
        if ((unsigned)idx >= (unsigned)KCODES) idx = 0;   // never fault on a dropped token
        fin[tid] = idx;
        out_idx[tokBase + tid] = (float)idx;
    }
    __syncthreads();
    for (int e2 = tid; e2 < BM * (DIMS / 4); e2 += 256) {
        int r = e2 >> 6, c4 = e2 & 63;
        float4 v = *(const float4*)(cb + (size_t)fin[r] * DIMS + c4 * 4);
        *(float4*)(out_q + (size_t)(tokBase + r) * DIMS + c4 * 4) = v;
    }
}

extern "C" void kernel_launch(void* const* d_in, const int* in_sizes, int n_in,
                              void* d_out, int out_size, void* d_ws, size_t ws_size,
                              hipStream_t stream) {
    const float* h  = (const float*)d_in[0];   // [32768, 256]
    const float* cb = (const float*)d_in[1];   // [8192, 256]
    float* out_q   = (float*)d_out;
    float* out_idx = (float*)d_out + (size_t)NTOK * DIMS;

    float* c2 = (float*)d_ws;                                       // 32 KB
    unsigned short* cbbf = (unsigned short*)((char*)d_ws + 32768);  // 4 MB
    const size_t needed = 32768 + (size_t)KCODES * DIMS * 2;
    const int wsbf = (ws_size >= needed) ? 1 : 0;

    prep_kernel<<<KCODES / 4, 256, 0, stream>>>(cb, c2, cbbf, wsbf);
    if (wsbf)
        vq_main<true><<<NTOK / BM, 256, 0, stream>>>(h, cb, cbbf, c2, out_q, out_idx);
    else
        vq_main<false><<<NTOK / BM, 256, 0, stream>>>(h, cb, (const unsigned short*)nullptr, c2, out_q, out_idx);
}